// Round 1
// baseline (563.842 us; speedup 1.0000x reference)
//
#include <hip/hip_runtime.h>
#include <stdint.h>

// hierarchical cluster assignment: L=6, N=64, Q0=64, C=256 (fixed by reference setup)
#define NSLICE 384   // L*N
#define QMAX   64
#define CDIM   256

__launch_bounds__(256, 2)
__global__ void hca_kernel(const float* __restrict__ in, float* __restrict__ out) {
    // cen: 64 rows x 256 f32 = 64KB ; dist: 64x64 f32 = 16KB (diagonal stores sq[q])
    __shared__ float cen[QMAX * CDIM];
    __shared__ float dist[QMAX * QMAX];

    const int tid  = threadIdx.x;
    const int lane = tid & 63;
    const int w    = tid >> 6;
    const int slice = blockIdx.x;
    const float* src = in + (size_t)slice * (QMAX * CDIM);

    // ---- load slice into LDS (coalesced float4) ----
    {
        const float4* s4 = (const float4*)src;
        float4* c4 = (float4*)cen;
        #pragma unroll
        for (int i = 0; i < (QMAX * CDIM / 4) / 256; ++i)
            c4[tid + i * 256] = s4[tid + i * 256];
    }
    __syncthreads();

    // wave-level dot of rows ra,rb: lane handles 4 consecutive elems (fma chain),
    // then binary-tree butterfly across 64 lanes. Deterministic tree; all lanes get sum.
    auto wdot = [&](int ra, int rb) -> float {
        const float4 a = ((const float4*)(cen + ra * CDIM))[lane];
        const float4 b = ((const float4*)(cen + rb * CDIM))[lane];
        float t = a.x * b.x;
        t = fmaf(a.y, b.y, t);
        t = fmaf(a.z, b.z, t);
        t = fmaf(a.w, b.w, t);
        #pragma unroll
        for (int off = 1; off < 64; off <<= 1)
            t += __shfl_xor(t, off, 64);
        return t;
    };

    // ---- initial sq[q] into diagonal ----
    for (int q = w; q < QMAX; q += 4) {
        float s = wdot(q, q);
        if (lane == 0) dist[q * QMAX + q] = s;
    }
    __syncthreads();

    // ---- initial off-diagonal distances (mirror d2 = sq+sq-2*gram, sqrt(max(,0))) ----
    for (int q = w; q < QMAX; q += 4) {
        float sqq = dist[q * QMAX + q];
        for (int p = q + 1; p < QMAX; ++p) {
            float s = wdot(q, p);
            if (lane == 0) {
                float sqp = dist[p * QMAX + p];
                float d2 = sqq + sqp - 2.0f * s;
                float d  = sqrtf(fmaxf(d2, 0.0f));
                dist[q * QMAX + p] = d;
                dist[p * QMAX + q] = d;
            }
        }
    }
    __syncthreads();

    // ---- 62 serial merge steps ----
    for (int Q = QMAX; Q > 2; --Q) {
        // argmin over off-diagonal, key = (dist_bits<<12) | (q*Q + lane)
        // -> min dist first, then min row-major flat index (matches jnp.argmin tiebreak).
        // All 4 waves scan redundantly: no cross-wave reduce, every thread learns x,y.
        unsigned long long kmin = ~0ull;
        if (lane < Q) {
            for (int q = 0; q < Q; ++q) {
                if (q == lane) continue;                  // exclude diagonal (holds sq)
                float d = dist[q * QMAX + lane];
                unsigned long long key =
                    ((unsigned long long)__float_as_uint(d) << 12) |
                    (unsigned)(q * Q + lane);
                kmin = kmin < key ? kmin : key;
            }
        }
        #pragma unroll
        for (int off = 1; off < 64; off <<= 1) {
            unsigned long long o = __shfl_xor(kmin, off, 64);
            kmin = kmin < o ? kmin : o;
        }
        int flat = (int)(kmin & 0xFFFull);
        int x = flat / Q;
        int y = flat - x * Q;        // x < y always (symmetric dist, row-major tiebreak)

        __syncthreads();             // all waves done reading dist before mutation

        // center merge: thread owns one column c -> no cross-thread hazard
        {
            int c = tid;
            float ax = cen[x * CDIM + c];
            float ay = cen[y * CDIM + c];
            float lv = cen[(Q - 1) * CDIM + c];
            cen[x * CDIM + c] = (ax + ay) * 0.5f;        // bit-exact vs reference
            if (y != Q - 1) cen[y * CDIM + c] = lv;      // bit-exact copy
        }
        // dist row/col Q-1 -> y (bit-exact copy), and sq[Q-1] -> sq[y]
        if (y != Q - 1) {
            if (tid == 0) dist[y * QMAX + y] = dist[(Q - 1) * QMAX + (Q - 1)];
            for (int p = tid; p < Q - 1; p += 256) {
                if (p == y) continue;
                float v = dist[(Q - 1) * QMAX + p];
                dist[y * QMAX + p] = v;
                dist[p * QMAX + y] = v;
            }
        }
        __syncthreads();

        // fresh sq[x] (all waves redundantly, identical bits) + fresh row/col x
        float sxx = wdot(x, x);
        if (w == 0 && lane == 0) dist[x * QMAX + x] = sxx;
        int newQ = Q - 1;
        for (int p = w; p < newQ; p += 4) {
            if (p == x) continue;
            float s = wdot(x, p);
            if (lane == 0) {
                float sqp = dist[p * QMAX + p];
                float d2 = sxx + sqp - 2.0f * s;
                float d  = sqrtf(fmaxf(d2, 0.0f));
                dist[x * QMAX + p] = d;
                dist[p * QMAX + x] = d;
            }
        }
        __syncthreads();
    }

    // ---- write final 2 centers (rows 0..1 are contiguous in LDS) ----
    float* dst = out + (size_t)slice * (2 * CDIM);
    for (int i = tid; i < 2 * CDIM; i += 256)
        dst[i] = cen[i];
}

extern "C" void kernel_launch(void* const* d_in, const int* in_sizes, int n_in,
                              void* d_out, int out_size, void* d_ws, size_t ws_size,
                              hipStream_t stream) {
    (void)in_sizes; (void)n_in; (void)d_ws; (void)ws_size; (void)out_size;
    const float* in = (const float*)d_in[0];
    float* out = (float*)d_out;
    hca_kernel<<<NSLICE, 256, 0, stream>>>(in, out);
}

// Round 2
// 265.622 us; speedup vs baseline: 2.1227x; 2.1227x over previous
//
#include <hip/hip_runtime.h>
#include <stdint.h>

// hierarchical cluster assignment: L=6, N=64, Q0=64, C=256 (fixed by reference setup)
#define NSLICE 384
#define QMAX   64
#define CDIM   256
#define NTHR   512
#define NWAVE  8

// Canonical GCN wave64 sum reduction via DPP (VALU-only, off the DS pipe).
// Result valid in lane 63. old=0 + add makes every masked/invalid-lane case a +0.
__device__ __forceinline__ float dpp_sum64(float v) {
#define DPP_ADD(c) v += __int_as_float(__builtin_amdgcn_update_dpp(0, __float_as_int(v), c, 0xf, 0xf, true))
    DPP_ADD(0x111); // row_shr:1
    DPP_ADD(0x112); // row_shr:2
    DPP_ADD(0x114); // row_shr:4
    DPP_ADD(0x118); // row_shr:8  -> lane15 of each row = row sum
    DPP_ADD(0x142); // row_bcast:15 -> lane31 = sum(0..31), lane63 = sum(32..63)
    DPP_ADD(0x143); // row_bcast:31 -> lane63 = sum(0..63)
#undef DPP_ADD
    return v;
}

__launch_bounds__(NTHR, 4)
__global__ void hca_kernel(const float* __restrict__ in, float* __restrict__ out) {
    // cen 64x256 f32 = 64KB ; dist 64x64 f32 = 16KB (diag stores sq). Total exactly 80KB
    // -> 2 blocks/CU (160KB). Do NOT add any __shared__ byte.
    __shared__ __align__(16) float cen[QMAX * CDIM];
    __shared__ __align__(16) float dist[QMAX * QMAX];

    const int tid  = threadIdx.x;
    const int lane = tid & 63;
    const int w    = tid >> 6;
    const int slice = blockIdx.x;
    const float* src = in + (size_t)slice * (QMAX * CDIM);
    float* dst = out + (size_t)slice * (2 * CDIM);   // dst[0] doubles as (x,y) broadcast slot

    // ---- load slice into LDS ----
    {
        const float4* s4 = (const float4*)src;
        float4* c4 = (float4*)cen;
        #pragma unroll
        for (int i = 0; i < (QMAX * CDIM / 4) / NTHR; ++i)
            c4[tid + i * NTHR] = s4[tid + i * NTHR];
    }
    __syncthreads();

    // ---- sq[q] -> diagonal ----
    for (int q = w; q < QMAX; q += NWAVE) {
        const float4 a = ((const float4*)(cen + q * CDIM))[lane];
        float t = a.x * a.x; t = fmaf(a.y, a.y, t); t = fmaf(a.z, a.z, t); t = fmaf(a.w, a.w, t);
        float s = dpp_sum64(t);
        if (lane == 63) dist[q * QMAX + q] = s;
    }
    __syncthreads();

    // ---- initial distances (A-row cached in regs, 1 ds_read_b128 per dot) ----
    for (int q = w; q < QMAX; q += NWAVE) {
        const float4 a = ((const float4*)(cen + q * CDIM))[lane];
        const float sqq = dist[q * QMAX + q];
        for (int p = q + 1; p < QMAX; ++p) {
            float sqp = dist[p * QMAX + p];                       // broadcast read
            const float4 b = ((const float4*)(cen + p * CDIM))[lane];
            float t = a.x * b.x; t = fmaf(a.y, b.y, t); t = fmaf(a.z, b.z, t); t = fmaf(a.w, b.w, t);
            float s = dpp_sum64(t);
            if (lane == 63) {
                float d2 = sqq + sqp - 2.0f * s;
                float d  = sqrtf(fmaxf(d2, 0.0f));
                dist[q * QMAX + p] = d;
                dist[p * QMAX + q] = d;
            }
        }
    }
    __syncthreads();

    // ---- 62 serial merge steps ----
    for (int Q = QMAX; Q > 2; --Q) {
        // argmin: wave 0 only, float4 scan. key = (dist_bits<<12) | (r*64+c):
        // min dist first, then min (r,c) lex — identical tie order to reference's r*Q+c.
        if (w == 0) {
            unsigned long long kmin = ~0ull;
            const int nvec = (Q + 3) >> 2;           // ceil(Q*64/256) float4-rows of 64 lanes
            for (int i = 0; i < nvec; ++i) {
                float4 dv = ((const float4*)dist)[i * 64 + lane];
                int base = i * 256 + lane * 4;
                #pragma unroll
                for (int e = 0; e < 4; ++e) {
                    int idx = base + e;
                    int r = idx >> 6, c = idx & 63;
                    float d = (&dv.x)[e];
                    if (r < Q && c < Q && r != c) {  // skip stale rows/cols and diag(=sq)
                        unsigned long long key =
                            ((unsigned long long)__float_as_uint(d) << 12) | (unsigned)idx;
                        kmin = kmin < key ? kmin : key;
                    }
                }
            }
            #pragma unroll
            for (int off = 1; off < 64; off <<= 1) {
                unsigned long long o = __shfl_xor(kmin, off, 64);
                kmin = kmin < o ? kmin : o;
            }
            if (lane == 0)
                __hip_atomic_store((unsigned*)dst, (unsigned)(kmin & 0xFFFu),
                                   __ATOMIC_RELAXED, __HIP_MEMORY_SCOPE_WORKGROUP);
        }
        __syncthreads();
        const unsigned flat = __hip_atomic_load((const unsigned*)dst,
                                 __ATOMIC_RELAXED, __HIP_MEMORY_SCOPE_WORKGROUP);
        const int x = (int)(flat >> 6), y = (int)(flat & 63);    // x < y guaranteed

        // merge centers: thread owns one column
        if (tid < CDIM) {
            const int c = tid;
            float ax = cen[x * CDIM + c];
            float ay = cen[y * CDIM + c];
            float lv = cen[(Q - 1) * CDIM + c];
            cen[x * CDIM + c] = (ax + ay) * 0.5f;    // bit-exact vs reference
            if (y != Q - 1) cen[y * CDIM + c] = lv;  // bit-exact copy
        }
        // move dist row/col Q-1 -> y (bit-exact copies)
        if (y != Q - 1) {
            if (tid == 0) dist[y * QMAX + y] = dist[(Q - 1) * QMAX + (Q - 1)];
            for (int p = tid; p < Q - 1; p += NTHR) {
                if (p != y) {
                    float v = dist[(Q - 1) * QMAX + p];
                    dist[y * QMAX + p] = v;
                    dist[p * QMAX + y] = v;
                }
            }
        }
        __syncthreads();

        // fresh row/col x vs all survivors (merged row cached in regs)
        const int nQ = Q - 1;
        const float4 a = ((const float4*)(cen + x * CDIM))[lane];
        float t = a.x * a.x; t = fmaf(a.y, a.y, t); t = fmaf(a.z, a.z, t); t = fmaf(a.w, a.w, t);
        const float sxx = dpp_sum64(t);              // lane 63 (identical bits in every wave)
        if (w == 0 && lane == 63) dist[x * QMAX + x] = sxx;
        for (int p = w; p < nQ; p += NWAVE) {
            if (p == x) continue;
            float sqp = dist[p * QMAX + p];
            const float4 b = ((const float4*)(cen + p * CDIM))[lane];
            float u = a.x * b.x; u = fmaf(a.y, b.y, u); u = fmaf(a.z, b.z, u); u = fmaf(a.w, b.w, u);
            float s = dpp_sum64(u);
            if (lane == 63) {
                float d2 = sxx + sqp - 2.0f * s;
                float d  = sqrtf(fmaxf(d2, 0.0f));
                dist[x * QMAX + p] = d;
                dist[p * QMAX + x] = d;
            }
        }
        __syncthreads();
    }

    // ---- final 2 centers ----
    for (int i = tid; i < 2 * CDIM; i += NTHR)
        dst[i] = cen[i];
}

extern "C" void kernel_launch(void* const* d_in, const int* in_sizes, int n_in,
                              void* d_out, int out_size, void* d_ws, size_t ws_size,
                              hipStream_t stream) {
    (void)in_sizes; (void)n_in; (void)d_ws; (void)ws_size; (void)out_size;
    const float* in = (const float*)d_in[0];
    float* out = (float*)d_out;
    hca_kernel<<<NSLICE, NTHR, 0, stream>>>(in, out);
}

// Round 4
// 229.152 us; speedup vs baseline: 2.4606x; 1.1592x over previous
//
#include <hip/hip_runtime.h>
#include <stdint.h>

// hierarchical cluster assignment: L=6, N=64, Q0=64, C=256 (fixed by reference setup)
#define NSLICE 384
#define QMAX   64
#define CDIM   256
#define NTHR   512
#define NWAVE  8

// Wave64 sum via DPP (VALU-only). Result valid in lane 63. old=0+add -> masked lanes add 0.
// NOTE: identical tree to r2 -> bit-identical sums -> identical merge trajectory.
__device__ __forceinline__ float dpp_sum64(float v) {
#define DPP_ADD(c) v += __int_as_float(__builtin_amdgcn_update_dpp(0, __float_as_int(v), c, 0xf, 0xf, true))
    DPP_ADD(0x111); // row_shr:1
    DPP_ADD(0x112); // row_shr:2
    DPP_ADD(0x114); // row_shr:4
    DPP_ADD(0x118); // row_shr:8
    DPP_ADD(0x142); // row_bcast:15
    DPP_ADD(0x143); // row_bcast:31
#undef DPP_ADD
    return v;
}

// one DPP step of u32 min; old=v + bound_ctrl=false -> invalid lanes are identity.
// CTRL must be a compile-time constant -> template parameter.
template<int CTRL>
__device__ __forceinline__ unsigned dpp_min_step(unsigned v) {
    unsigned o = (unsigned)__builtin_amdgcn_update_dpp((int)v, (int)v, CTRL, 0xf, 0xf, false);
    return v < o ? v : o;
}

// full-wave u32 min, broadcast to all lanes via readlane (pure VALU, no DS pipe)
__device__ __forceinline__ unsigned wave_min_bcast(unsigned v) {
    v = dpp_min_step<0x111>(v);
    v = dpp_min_step<0x112>(v);
    v = dpp_min_step<0x114>(v);
    v = dpp_min_step<0x118>(v);
    v = dpp_min_step<0x142>(v);
    v = dpp_min_step<0x143>(v);
    return (unsigned)__builtin_amdgcn_readlane((int)v, 63);
}

// min over groups of 8 consecutive lanes where lane l holds value[l&7]; all lanes get result
__device__ __forceinline__ unsigned oct_min_all(unsigned v) {
    v = dpp_min_step<0xB1>(v);   // quad_perm [1,0,3,2]  (xor 1)
    v = dpp_min_step<0x4E>(v);   // quad_perm [2,3,0,1]  (xor 2)
    v = dpp_min_step<0x124>(v);  // row_ror:4            (cross-quad)
    return v;
}

__launch_bounds__(NTHR, 4)
__global__ void hca_kernel(const float* __restrict__ in, float* __restrict__ out) {
    // cen 64x256 f32 = 64KB ; dist 64x64 f32 = 16KB (diag stores sq). Exactly 80KB
    // -> 2 blocks/CU. Row 63 of dist is DEAD once Q<=63 -> reused as argmin scratch.
    __shared__ __align__(16) float cen[QMAX * CDIM];
    __shared__ __align__(16) float dist[QMAX * QMAX];

    const int tid  = threadIdx.x;
    const int lane = tid & 63;
    const int w    = tid >> 6;
    const int slice = blockIdx.x;
    const float* src = in + (size_t)slice * (QMAX * CDIM);
    float* dst = out + (size_t)slice * (2 * CDIM);

    // ---- load slice into LDS ----
    {
        const float4* s4 = (const float4*)src;
        float4* c4 = (float4*)cen;
        #pragma unroll
        for (int i = 0; i < (QMAX * CDIM / 4) / NTHR; ++i)
            c4[tid + i * NTHR] = s4[tid + i * NTHR];
    }
    __syncthreads();

    // ---- init: wave w owns rows {w, w+8, ..., w+56}, cached in registers ----
    float4 A[8];
    #pragma unroll
    for (int r = 0; r < 8; ++r)
        A[r] = ((const float4*)(cen + (w + 8 * r) * CDIM))[lane];

    // sq[q] -> diagonal
    #pragma unroll
    for (int r = 0; r < 8; ++r) {
        float t = A[r].x * A[r].x;
        t = fmaf(A[r].y, A[r].y, t); t = fmaf(A[r].z, A[r].z, t); t = fmaf(A[r].w, A[r].w, t);
        float s = dpp_sum64(t);
        if (lane == 63) dist[(w + 8 * r) * QMAX + (w + 8 * r)] = s;
    }
    __syncthreads();

    // off-diagonal: read each B row ONCE, up to 8 dots per ds_read_b128
    float sqq[8];
    #pragma unroll
    for (int r = 0; r < 8; ++r) sqq[r] = dist[(w + 8 * r) * QMAX + (w + 8 * r)];
    for (int p = 1; p < QMAX; ++p) {
        const float4 b = ((const float4*)(cen + p * CDIM))[lane];
        const float sqp = dist[p * QMAX + p];         // broadcast read
        #pragma unroll
        for (int r = 0; r < 8; ++r) {
            const int q = w + 8 * r;                  // wave-uniform
            if (q < p) {
                float t = A[r].x * b.x;
                t = fmaf(A[r].y, b.y, t); t = fmaf(A[r].z, b.z, t); t = fmaf(A[r].w, b.w, t);
                float s = dpp_sum64(t);
                if (lane == 63) {
                    float d2 = sqq[r] + sqp - 2.0f * s;
                    float d  = sqrtf(fmaxf(d2, 0.0f));
                    dist[q * QMAX + p] = d;
                    dist[p * QMAX + q] = d;
                }
            }
        }
    }
    __syncthreads();

    // ---- 62 serial merge steps ----
    for (int Q = QMAX; Q > 2; --Q) {
        // --- argmin: all 8 waves scan in parallel (wave w: float4-rows 2w, 2w+1) ---
        // key = (d_bits, r*64+c) lexicographic == reference's (dist, r*Q+c) order.
        unsigned bdb = 0xFFFFFFFFu, bidx = 0xFFFu;
        const bool full = (Q == QMAX);                // first iter: row 63 live -> no scratch
        const int i0 = full ? 0 : 2 * w;
        const int i1 = full ? 16 : 2 * w + 2;
        for (int i = i0; i < i1; ++i) {
            if (4 * i >= Q) continue;                 // wave-uniform skip of dead rows
            float4 dv = ((const float4*)dist)[i * 64 + lane];
            int base = i * 256 + lane * 4;
            #pragma unroll
            for (int e = 0; e < 4; ++e) {
                int idx = base + e;
                int r = idx >> 6, c = idx & 63;
                unsigned db = __float_as_uint((&dv.x)[e]);  // d>=0: bits order == float order
                bool ok = (r < Q) & (c < Q) & (r != c);     // skip stale + diag(=sq)
                bool lt = ok & ((db < bdb) | ((db == bdb) & ((unsigned)idx < bidx)));
                bdb  = lt ? db : bdb;
                bidx = lt ? (unsigned)idx : bidx;
            }
        }
        unsigned gdb  = wave_min_bcast(bdb);
        unsigned cand = (bdb == gdb) ? bidx : 0xFFFFFFFFu;
        unsigned gidx = wave_min_bcast(cand);

        unsigned flat;
        if (full) {
            __syncthreads();                          // scans done before merge mutates dist
            flat = gidx;                              // every wave scanned everything
        } else {
            if (lane == 0)                            // partial -> scratch (dead row 63)
                ((unsigned long long*)(dist + 63 * QMAX))[w] =
                    ((unsigned long long)gdb << 32) | gidx;
            __syncthreads();
            unsigned long long k = ((const unsigned long long*)(dist + 63 * QMAX))[lane & 7];
            unsigned hi = (unsigned)(k >> 32), lo = (unsigned)k;
            unsigned ghi = oct_min_all(hi);
            unsigned c2  = (hi == ghi) ? lo : 0xFFFFFFFFu;
            flat = oct_min_all(c2);
        }
        const int x = (int)(flat >> 6), y = (int)(flat & 63);  // x < y guaranteed

        // --- merge (no barrier needed: writes are disjoint from combine's row-63 reads) ---
        if (tid < CDIM) {
            const int c = tid;
            float ax = cen[x * CDIM + c];
            float ay = cen[y * CDIM + c];
            float lv = cen[(Q - 1) * CDIM + c];
            cen[x * CDIM + c] = (ax + ay) * 0.5f;     // bit-exact vs reference
            if (y != Q - 1) cen[y * CDIM + c] = lv;   // bit-exact copy
        }
        if (y != Q - 1) {                             // dist row/col Q-1 -> y (bit-exact)
            if (tid == 0) dist[y * QMAX + y] = dist[(Q - 1) * QMAX + (Q - 1)];
            for (int p = tid; p < Q - 1; p += NTHR) {
                if (p != y) {
                    float v = dist[(Q - 1) * QMAX + p];
                    dist[y * QMAX + p] = v;
                    dist[p * QMAX + y] = v;
                }
            }
        }
        __syncthreads();

        // --- fresh row/col x vs survivors (merged row cached in regs) ---
        const int nQ = Q - 1;
        const float4 a = ((const float4*)(cen + x * CDIM))[lane];
        float t = a.x * a.x; t = fmaf(a.y, a.y, t); t = fmaf(a.z, a.z, t); t = fmaf(a.w, a.w, t);
        const float sxx = dpp_sum64(t);               // identical bits in every wave
        if (w == 0 && lane == 63) dist[x * QMAX + x] = sxx;
        for (int p = w; p < nQ; p += NWAVE) {
            if (p == x) continue;
            float sqp = dist[p * QMAX + p];
            const float4 b = ((const float4*)(cen + p * CDIM))[lane];
            float u = a.x * b.x; u = fmaf(a.y, b.y, u); u = fmaf(a.z, b.z, u); u = fmaf(a.w, b.w, u);
            float s = dpp_sum64(u);
            if (lane == 63) {
                float d2 = sxx + sqp - 2.0f * s;
                float d  = sqrtf(fmaxf(d2, 0.0f));
                dist[x * QMAX + p] = d;
                dist[p * QMAX + x] = d;
            }
        }
        __syncthreads();
    }

    // ---- final 2 centers ----
    for (int i = tid; i < 2 * CDIM; i += NTHR)
        dst[i] = cen[i];
}

extern "C" void kernel_launch(void* const* d_in, const int* in_sizes, int n_in,
                              void* d_out, int out_size, void* d_ws, size_t ws_size,
                              hipStream_t stream) {
    (void)in_sizes; (void)n_in; (void)d_ws; (void)ws_size; (void)out_size;
    const float* in = (const float*)d_in[0];
    float* out = (float*)d_out;
    hca_kernel<<<NSLICE, NTHR, 0, stream>>>(in, out);
}